// Round 1
// baseline (624.797 us; speedup 1.0000x reference)
//
#include <hip/hip_runtime.h>
#include <math.h>

// Problem constants
#define EMBED 1024
#define NHEAD 8
#define HDIM 128
#define TSEQ 128      // leaf seq len (T)
#define TK 255        // node count (2T-1)
#define BATCH 4
#define LQ 128        // target len
#define BH 32         // BATCH*NHEAD

// ---------------- Tiled fp32 GEMM: C[m,n] = (sum_k A[m,k]*B[n,k] + bias[n]) * scale
// Supports a per-blockIdx.z offset on A/B/C so batched head-GEMMs reuse it.
#define GBM 64
#define GBN 64
#define GBK 16

__global__ __launch_bounds__(256) void sgemm_abt(
    const float* __restrict__ A, int lda, long long aoffz,
    const float* __restrict__ B, int ldb, long long boffz,
    const float* __restrict__ bias,
    float* __restrict__ C, int ldc, long long coffz,
    int M, int N, int K, float scale)
{
    __shared__ float As[GBK][GBM + 4];
    __shared__ float Bs[GBK][GBN + 4];
    const int z = blockIdx.z;
    const float* Ab = A + (long long)z * aoffz;
    const float* Bb = B + (long long)z * boffz;
    float* Cb = C + (long long)z * coffz;
    const int m0 = blockIdx.y * GBM;
    const int n0 = blockIdx.x * GBN;
    const int t = threadIdx.x;         // 0..255
    const int tx = t & 15, ty = t >> 4;

    float acc[4][4] = {};
    for (int k0 = 0; k0 < K; k0 += GBK) {
        #pragma unroll
        for (int r = 0; r < 4; ++r) {
            int idx = t + r * 256;
            int mi = idx / GBK, ki = idx % GBK;
            int m = m0 + mi;
            As[ki][mi] = (m < M) ? Ab[(long long)m * lda + (k0 + ki)] : 0.f;
        }
        #pragma unroll
        for (int r = 0; r < 4; ++r) {
            int idx = t + r * 256;
            int ni = idx / GBK, ki = idx % GBK;
            int n = n0 + ni;
            Bs[ki][ni] = (n < N) ? Bb[(long long)n * ldb + (k0 + ki)] : 0.f;
        }
        __syncthreads();
        #pragma unroll
        for (int kk = 0; kk < GBK; ++kk) {
            float a[4], bb[4];
            #pragma unroll
            for (int i = 0; i < 4; ++i) a[i] = As[kk][ty * 4 + i];
            #pragma unroll
            for (int j = 0; j < 4; ++j) bb[j] = Bs[kk][tx * 4 + j];
            #pragma unroll
            for (int i = 0; i < 4; ++i)
                #pragma unroll
                for (int j = 0; j < 4; ++j)
                    acc[i][j] += a[i] * bb[j];
        }
        __syncthreads();
    }
    #pragma unroll
    for (int i = 0; i < 4; ++i) {
        int m = m0 + ty * 4 + i;
        if (m >= M) continue;
        #pragma unroll
        for (int j = 0; j < 4; ++j) {
            int n = n0 + tx * 4 + j;
            if (n >= N) continue;
            float v = acc[i][j];
            if (bias) v += bias[n];
            Cb[(long long)m * ldc + n] = v * scale;
        }
    }
}

// ---------------- Containment-sum + softmax, one block per (bh, t) row.
// raw: [BH][LQ][TK], indices: [BATCH][TK][2] int32, w(out): [BH][LQ][TK]
__global__ __launch_bounds__(256) void tree_scores_softmax(
    const float* __restrict__ raw,
    const int* __restrict__ indices,
    float* __restrict__ w)
{
    const int blk = blockIdx.x;          // 0 .. BH*LQ-1
    const int bh = blk / LQ, tq = blk % LQ;
    const int b = bh / NHEAD;
    const int tid = threadIdx.x;

    __shared__ float raws[256];
    __shared__ int rs[256], cs[256];
    __shared__ float sred[4];

    const float* rrow = raw + ((long long)bh * LQ + tq) * TK;
    if (tid < TK) {
        raws[tid] = rrow[tid];
        rs[tid] = indices[(b * TK + tid) * 2 + 0];
        cs[tid] = indices[(b * TK + tid) * 2 + 1];
    }
    __syncthreads();

    float score = -INFINITY;
    if (tid < TK) {
        const int rn = rs[tid], cn = cs[tid];
        float s = 0.f;
        for (int m = 0; m < TK; ++m) {
            if (rn <= rs[m] && cs[m] <= cn) s += raws[m];
        }
        score = s;
    }

    // block max
    float vmax = score;
    #pragma unroll
    for (int off = 32; off > 0; off >>= 1) vmax = fmaxf(vmax, __shfl_xor(vmax, off));
    if ((tid & 63) == 0) sred[tid >> 6] = vmax;
    __syncthreads();
    const float rowmax = fmaxf(fmaxf(sred[0], sred[1]), fmaxf(sred[2], sred[3]));

    float e = (tid < TK) ? expf(score - rowmax) : 0.f;
    float ssum = e;
    #pragma unroll
    for (int off = 32; off > 0; off >>= 1) ssum += __shfl_xor(ssum, off);
    __syncthreads();
    if ((tid & 63) == 0) sred[tid >> 6] = ssum;
    __syncthreads();
    const float total = sred[0] + sred[1] + sred[2] + sred[3];

    if (tid < TK) w[((long long)bh * LQ + tq) * TK + tid] = e / total;
}

// ---------------- PV: attn[(t*B+b)*E + h*HDIM + d] = sum_n w[bh][t][n] * v_proj[(n*B+b)*E + h*HDIM + d]
__global__ __launch_bounds__(256) void pv_kernel(
    const float* __restrict__ w,
    const float* __restrict__ vproj,
    float* __restrict__ attn)
{
    const int blk = blockIdx.x;          // BH * (LQ/2)
    const int bh = blk / (LQ / 2), tp = blk % (LQ / 2);
    const int b = bh / NHEAD, h = bh % NHEAD;
    const int tid = threadIdx.x;         // 256 = 2 rows x 128 d
    const int lt = tid >> 7;             // 0/1
    const int d = tid & 127;
    const int tq = tp * 2 + lt;

    __shared__ float wl[2][TK + 1];
    for (int i = tid; i < 2 * TK; i += 256) {
        int row = i / TK, n = i % TK;
        wl[row][n] = w[((long long)bh * LQ + tp * 2 + row) * TK + n];
    }
    __syncthreads();

    const float* vbase = vproj + (long long)b * EMBED + h * HDIM + d;
    float acc = 0.f;
    for (int n = 0; n < TK; ++n) {
        acc += wl[lt][n] * vbase[(long long)n * (BATCH * EMBED)];
    }
    attn[((long long)tq * BATCH + b) * EMBED + h * HDIM + d] = acc;
}

extern "C" void kernel_launch(void* const* d_in, const int* in_sizes, int n_in,
                              void* d_out, int out_size, void* d_ws, size_t ws_size,
                              hipStream_t stream) {
    const float* query   = (const float*)d_in[0];   // [128,4,1024]
    const float* key_t   = (const float*)d_in[1];   // [255,4,1024]
    const float* value   = (const float*)d_in[2];   // [255,4,1024]
    const int*   indices = (const int*)d_in[3];     // [4,255,2]
    const float* ipw     = (const float*)d_in[4];   // [3072,1024]
    const float* ipb     = (const float*)d_in[5];   // [3072]
    const float* opw     = (const float*)d_in[6];   // [1024,1024]
    const float* opb     = (const float*)d_in[7];   // [1024]
    float* out = (float*)d_out;

    float* ws = (float*)d_ws;
    const int MQ = LQ * BATCH;     // 512
    const int MK = TK * BATCH;     // 1020
    float* q_proj = ws;                          // [512][1024]
    float* k_proj = q_proj + (long long)MQ * EMBED;   // [1020][1024]
    float* v_proj = k_proj + (long long)MK * EMBED;   // [1020][1024]
    float* rawbuf = v_proj + (long long)MK * EMBED;   // [32][128][255]
    float* wsoft  = rawbuf + (long long)BH * LQ * TK; // [32][128][255]
    float* attn   = wsoft  + (long long)BH * LQ * TK; // [512][1024]

    const float qscale = 0.08838834764831843f;  // 128^-0.5

    // q projection: (query @ wq.T + bq) * scale
    sgemm_abt<<<dim3(EMBED / GBN, (MQ + GBM - 1) / GBM, 1), 256, 0, stream>>>(
        query, EMBED, 0, ipw, EMBED, 0, ipb,
        q_proj, EMBED, 0, MQ, EMBED, EMBED, qscale);
    // k projection
    sgemm_abt<<<dim3(EMBED / GBN, (MK + GBM - 1) / GBM, 1), 256, 0, stream>>>(
        key_t, EMBED, 0, ipw + (long long)EMBED * EMBED, EMBED, 0, ipb + EMBED,
        k_proj, EMBED, 0, MK, EMBED, EMBED, 1.f);
    // v projection
    sgemm_abt<<<dim3(EMBED / GBN, (MK + GBM - 1) / GBM, 1), 256, 0, stream>>>(
        value, EMBED, 0, ipw + 2LL * EMBED * EMBED, EMBED, 0, ipb + 2 * EMBED,
        v_proj, EMBED, 0, MK, EMBED, EMBED, 1.f);

    // raw[bh][t][n] = q_row(t) . k_row(n) per head; z = bh = b*8+h → col offset z*128
    sgemm_abt<<<dim3((TK + GBN - 1) / GBN, LQ / GBM, BH), 256, 0, stream>>>(
        q_proj, BATCH * EMBED, HDIM,
        k_proj, BATCH * EMBED, HDIM,
        nullptr,
        rawbuf, TK, (long long)LQ * TK,
        LQ, TK, HDIM, 1.f);

    // containment sum + softmax
    tree_scores_softmax<<<dim3(BH * LQ), 256, 0, stream>>>(rawbuf, indices, wsoft);

    // attn = w @ v
    pv_kernel<<<dim3(BH * (LQ / 2)), 256, 0, stream>>>(wsoft, v_proj, attn);

    // out projection
    sgemm_abt<<<dim3(EMBED / GBN, (MQ + GBM - 1) / GBM, 1), 256, 0, stream>>>(
        attn, EMBED, 0, opw, EMBED, 0, opb,
        out, EMBED, 0, MQ, EMBED, EMBED, 1.f);
}

// Round 2
// 276.628 us; speedup vs baseline: 2.2586x; 2.2586x over previous
//
#include <hip/hip_runtime.h>
#include <math.h>

// Problem constants
#define EMBED 1024
#define NHEAD 8
#define HDIM 128
#define TK 255
#define BATCH 4
#define LQ 128
#define BH 32

typedef __attribute__((ext_vector_type(4))) float f32x4;
typedef __attribute__((ext_vector_type(8))) short short8;

static __device__ __forceinline__ unsigned short f2bf(float f) {
    unsigned u = __float_as_uint(f);
    u += 0x7FFFu + ((u >> 16) & 1u);
    return (unsigned short)(u >> 16);
}
static __device__ __forceinline__ float bfbits2f(unsigned short s) {
    return __uint_as_float(((unsigned)s) << 16);
}

// ---- split-bf16 MFMA GEMM core: C[m,n] = (sum_k A[m,k]*B[n,k] + bias[n]) * scale
// Block tile 128x128, BK=64, 256 threads (4 waves, 2x2), per-wave 64x64.
// LDS: 4 planes (A_hi, A_lo, B_hi, B_lo), each [128 rows][64 bf16], row pitch 128B,
// XOR-swizzled: byte_in_row ^= (row&7)<<4  (kills 128B-stride bank conflicts).
#define BMT 128
#define BNT 128
#define BKT 64
#define PLANE 16384
#define AHOF 0
#define ALOF 16384
#define BHOF 32768
#define BLOF 49152

__device__ __forceinline__ void mgemm_core(
    const float* __restrict__ A, int lda,
    const float* __restrict__ B, int ldb,
    const float* __restrict__ bias,
    float* __restrict__ C, int ldc,
    int M, int N, int K, float scale,
    int m0, int n0, unsigned char* lds)
{
    const int t = threadIdx.x;
    const int lane = t & 63;
    const int wave = t >> 6;
    const int wm = wave >> 1, wn = wave & 1;

    f32x4 acc[4][4];
    #pragma unroll
    for (int i = 0; i < 4; ++i)
        #pragma unroll
        for (int j = 0; j < 4; ++j)
            #pragma unroll
            for (int e = 0; e < 4; ++e) acc[i][j][e] = 0.f;

    for (int k0 = 0; k0 < K; k0 += BKT) {
        // ---- stage: fp32 global -> hi/lo bf16 LDS planes (swizzled)
        #pragma unroll
        for (int i = 0; i < 4; ++i) {
            const int chunk = t + 256 * i;      // 1024 chunks of 8 floats per tile
            const int r = chunk >> 3, c8 = chunk & 7;
            const int kk = k0 + c8 * 8;
            const int off = r * 128 + ((c8 * 16) ^ ((r & 7) << 4));
            // A row
            {
                float4 f0 = make_float4(0.f, 0.f, 0.f, 0.f), f1 = f0;
                const int m = m0 + r;
                if (m < M) {
                    const float* p = A + (long long)m * lda + kk;
                    f0 = *(const float4*)p;
                    f1 = *(const float4*)(p + 4);
                }
                float fv[8] = {f0.x, f0.y, f0.z, f0.w, f1.x, f1.y, f1.z, f1.w};
                short8 hi, lo;
                #pragma unroll
                for (int j = 0; j < 8; ++j) {
                    unsigned short h = f2bf(fv[j]);
                    hi[j] = (short)h;
                    lo[j] = (short)f2bf(fv[j] - bfbits2f(h));
                }
                *(short8*)(lds + AHOF + off) = hi;
                *(short8*)(lds + ALOF + off) = lo;
            }
            // B row
            {
                float4 f0 = make_float4(0.f, 0.f, 0.f, 0.f), f1 = f0;
                const int n = n0 + r;
                if (n < N) {
                    const float* p = B + (long long)n * ldb + kk;
                    f0 = *(const float4*)p;
                    f1 = *(const float4*)(p + 4);
                }
                float fv[8] = {f0.x, f0.y, f0.z, f0.w, f1.x, f1.y, f1.z, f1.w};
                short8 hi, lo;
                #pragma unroll
                for (int j = 0; j < 8; ++j) {
                    unsigned short h = f2bf(fv[j]);
                    hi[j] = (short)h;
                    lo[j] = (short)f2bf(fv[j] - bfbits2f(h));
                }
                *(short8*)(lds + BHOF + off) = hi;
                *(short8*)(lds + BLOF + off) = lo;
            }
        }
        __syncthreads();

        // ---- compute: 2 k-slices of 32, 16 fragment pairs, 3 MFMAs each (hh, lh, hl)
        #pragma unroll
        for (int ks = 0; ks < 2; ++ks) {
            const int kb = ks * 64 + ((lane >> 4) << 4);
            short8 ah[4], al[4], bh[4], bl[4];
            #pragma unroll
            for (int fm = 0; fm < 4; ++fm) {
                const int row = wm * 64 + fm * 16 + (lane & 15);
                const int off = row * 128 + (kb ^ ((row & 7) << 4));
                ah[fm] = *(const short8*)(lds + AHOF + off);
                al[fm] = *(const short8*)(lds + ALOF + off);
            }
            #pragma unroll
            for (int fn = 0; fn < 4; ++fn) {
                const int row = wn * 64 + fn * 16 + (lane & 15);
                const int off = row * 128 + (kb ^ ((row & 7) << 4));
                bh[fn] = *(const short8*)(lds + BHOF + off);
                bl[fn] = *(const short8*)(lds + BLOF + off);
            }
            #pragma unroll
            for (int fm = 0; fm < 4; ++fm)
                #pragma unroll
                for (int fn = 0; fn < 4; ++fn) {
                    acc[fm][fn] = __builtin_amdgcn_mfma_f32_16x16x32_bf16(ah[fm], bh[fn], acc[fm][fn], 0, 0, 0);
                    acc[fm][fn] = __builtin_amdgcn_mfma_f32_16x16x32_bf16(al[fm], bh[fn], acc[fm][fn], 0, 0, 0);
                    acc[fm][fn] = __builtin_amdgcn_mfma_f32_16x16x32_bf16(ah[fm], bl[fn], acc[fm][fn], 0, 0, 0);
                }
        }
        __syncthreads();
    }

    // ---- epilogue: C[m,n], row = (lane>>4)*4 + reg, col = lane&15
    #pragma unroll
    for (int fm = 0; fm < 4; ++fm) {
        #pragma unroll
        for (int i = 0; i < 4; ++i) {
            const int m = m0 + wm * 64 + fm * 16 + ((lane >> 4) << 2) + i;
            if (m >= M) continue;
            #pragma unroll
            for (int fn = 0; fn < 4; ++fn) {
                const int n = n0 + wn * 64 + fn * 16 + (lane & 15);
                if (n >= N) continue;
                float v = acc[fm][fn][i];
                if (bias) v += bias[n];
                C[(long long)m * ldc + n] = v * scale;
            }
        }
    }
}

// ---- fused q/k/v projection: z selects which projection
__global__ __launch_bounds__(256) void qkv_proj_kernel(
    const float* __restrict__ query, const float* __restrict__ key_t,
    const float* __restrict__ value,
    const float* __restrict__ ipw, const float* __restrict__ ipb,
    float* __restrict__ q_proj, float* __restrict__ k_proj, float* __restrict__ v_proj,
    float qscale)
{
    __shared__ __align__(16) unsigned char lds[65536];
    const int z = blockIdx.z;
    const float* A; const float* B; const float* bias; float* C; int M; float scale;
    if (z == 0)      { A = query; B = ipw;                 bias = ipb;             C = q_proj; M = LQ * BATCH; scale = qscale; }
    else if (z == 1) { A = key_t; B = ipw + EMBED * EMBED; bias = ipb + EMBED;     C = k_proj; M = TK * BATCH; scale = 1.f; }
    else             { A = value; B = ipw + 2 * EMBED * EMBED; bias = ipb + 2 * EMBED; C = v_proj; M = TK * BATCH; scale = 1.f; }
    const int m0 = blockIdx.y * BMT;
    const int n0 = blockIdx.x * BNT;
    if (m0 >= M) return;
    mgemm_core(A, EMBED, B, EMBED, bias, C, EMBED, M, EMBED, EMBED, scale, m0, n0, lds);
}

// ---- per-head QK^T: raw[bh][t][n] = q_row(t) . k_row(n)
__global__ __launch_bounds__(256) void qk_kernel(
    const float* __restrict__ q_proj, const float* __restrict__ k_proj,
    float* __restrict__ raw)
{
    __shared__ __align__(16) unsigned char lds[65536];
    const int bh = blockIdx.z;
    const int b = bh >> 3, h = bh & 7;
    const float* A = q_proj + b * EMBED + h * HDIM;
    const float* B = k_proj + b * EMBED + h * HDIM;
    float* C = raw + (long long)bh * LQ * TK;
    mgemm_core(A, BATCH * EMBED, B, BATCH * EMBED, nullptr, C, TK,
               LQ, TK, HDIM, 1.f, 0, blockIdx.x * BNT, lds);
}

// ---- out projection
__global__ __launch_bounds__(256) void outproj_kernel(
    const float* __restrict__ attn, const float* __restrict__ opw,
    const float* __restrict__ opb, float* __restrict__ out)
{
    __shared__ __align__(16) unsigned char lds[65536];
    mgemm_core(attn, EMBED, opw, EMBED, opb, out, EMBED,
               LQ * BATCH, EMBED, EMBED, 1.f,
               blockIdx.y * BMT, blockIdx.x * BNT, lds);
}

// ---------------- Containment-sum + softmax, one block per (bh, t) row.
__global__ __launch_bounds__(256) void tree_scores_softmax(
    const float* __restrict__ raw,
    const int* __restrict__ indices,
    float* __restrict__ w)
{
    const int blk = blockIdx.x;
    const int bh = blk / LQ, tq = blk % LQ;
    const int b = bh / NHEAD;
    const int tid = threadIdx.x;

    __shared__ float raws[256];
    __shared__ int rs[256], cs[256];
    __shared__ float sred[4];

    const float* rrow = raw + ((long long)bh * LQ + tq) * TK;
    if (tid < TK) {
        raws[tid] = rrow[tid];
        rs[tid] = indices[(b * TK + tid) * 2 + 0];
        cs[tid] = indices[(b * TK + tid) * 2 + 1];
    }
    __syncthreads();

    float score = -INFINITY;
    if (tid < TK) {
        const int rn = rs[tid], cn = cs[tid];
        float s = 0.f;
        for (int m = 0; m < TK; ++m) {
            if (rn <= rs[m] && cs[m] <= cn) s += raws[m];
        }
        score = s;
    }

    float vmax = score;
    #pragma unroll
    for (int off = 32; off > 0; off >>= 1) vmax = fmaxf(vmax, __shfl_xor(vmax, off));
    if ((tid & 63) == 0) sred[tid >> 6] = vmax;
    __syncthreads();
    const float rowmax = fmaxf(fmaxf(sred[0], sred[1]), fmaxf(sred[2], sred[3]));

    float e = (tid < TK) ? expf(score - rowmax) : 0.f;
    float ssum = e;
    #pragma unroll
    for (int off = 32; off > 0; off >>= 1) ssum += __shfl_xor(ssum, off);
    __syncthreads();
    if ((tid & 63) == 0) sred[tid >> 6] = ssum;
    __syncthreads();
    const float total = sred[0] + sred[1] + sred[2] + sred[3];

    if (tid < TK) w[((long long)bh * LQ + tq) * TK + tid] = e / total;
}

// ---------------- PV: attn[(t*B+b)*E + h*HDIM + d] = sum_n w[bh][t][n] * v_proj[(n*B+b)*E + h*HDIM + d]
__global__ __launch_bounds__(256) void pv_kernel(
    const float* __restrict__ w,
    const float* __restrict__ vproj,
    float* __restrict__ attn)
{
    const int blk = blockIdx.x;
    const int bh = blk / (LQ / 2), tp = blk % (LQ / 2);
    const int b = bh / NHEAD, h = bh % NHEAD;
    const int tid = threadIdx.x;
    const int lt = tid >> 7;
    const int d = tid & 127;
    const int tq = tp * 2 + lt;

    __shared__ float wl[2][TK + 1];
    for (int i = tid; i < 2 * TK; i += 256) {
        int row = i / TK, n = i % TK;
        wl[row][n] = w[((long long)bh * LQ + tp * 2 + row) * TK + n];
    }
    __syncthreads();

    const float* vbase = vproj + (long long)b * EMBED + h * HDIM + d;
    float acc = 0.f;
    for (int n = 0; n < TK; ++n) {
        acc += wl[lt][n] * vbase[(long long)n * (BATCH * EMBED)];
    }
    attn[((long long)tq * BATCH + b) * EMBED + h * HDIM + d] = acc;
}

extern "C" void kernel_launch(void* const* d_in, const int* in_sizes, int n_in,
                              void* d_out, int out_size, void* d_ws, size_t ws_size,
                              hipStream_t stream) {
    const float* query   = (const float*)d_in[0];
    const float* key_t   = (const float*)d_in[1];
    const float* value   = (const float*)d_in[2];
    const int*   indices = (const int*)d_in[3];
    const float* ipw     = (const float*)d_in[4];
    const float* ipb     = (const float*)d_in[5];
    const float* opw     = (const float*)d_in[6];
    const float* opb     = (const float*)d_in[7];
    float* out = (float*)d_out;

    float* ws = (float*)d_ws;
    const int MQ = LQ * BATCH;     // 512
    const int MK = TK * BATCH;     // 1020
    float* q_proj = ws;
    float* k_proj = q_proj + (long long)MQ * EMBED;
    float* v_proj = k_proj + (long long)MK * EMBED;
    float* rawbuf = v_proj + (long long)MK * EMBED;
    float* wsoft  = rawbuf + (long long)BH * LQ * TK;
    float* attn   = wsoft  + (long long)BH * LQ * TK;

    const float qscale = 0.08838834764831843f;  // 128^-0.5

    // fused q/k/v projections (split-bf16 MFMA)
    qkv_proj_kernel<<<dim3(EMBED / BNT, 8, 3), 256, 0, stream>>>(
        query, key_t, value, ipw, ipb, q_proj, k_proj, v_proj, qscale);

    // per-head QK^T
    qk_kernel<<<dim3((TK + BNT - 1) / BNT, 1, BH), 256, 0, stream>>>(
        q_proj, k_proj, rawbuf);

    // containment sum + softmax
    tree_scores_softmax<<<dim3(BH * LQ), 256, 0, stream>>>(rawbuf, indices, wsoft);

    // attn = w @ v
    pv_kernel<<<dim3(BH * (LQ / 2)), 256, 0, stream>>>(wsoft, v_proj, attn);

    // out projection
    outproj_kernel<<<dim3(EMBED / BNT, MQ / BMT, 1), 256, 0, stream>>>(
        attn, opw, opb, out);
}

// Round 3
// 169.092 us; speedup vs baseline: 3.6950x; 1.6360x over previous
//
#include <hip/hip_runtime.h>
#include <math.h>

// Problem constants
#define EMBED 1024
#define NHEAD 8
#define HDIM 128
#define TK 255
#define BATCH 4
#define LQ 128
#define BH 32

typedef __attribute__((ext_vector_type(4))) float f32x4;
typedef __attribute__((ext_vector_type(8))) short short8;
typedef __attribute__((ext_vector_type(4))) short short4v;

static __device__ __forceinline__ unsigned short f2bf(float f) {
    unsigned u = __float_as_uint(f);
    u += 0x7FFFu + ((u >> 16) & 1u);
    return (unsigned short)(u >> 16);
}
static __device__ __forceinline__ float bfbits2f(unsigned short s) {
    return __uint_as_float(((unsigned)s) << 16);
}

__host__ __device__ constexpr int lds_bytes(int BM, int BN, bool AS, bool BS) {
    return BM * 128 * (1 + (AS ? 1 : 0)) + BN * 128 * (1 + (BS ? 1 : 0));
}

// ---- split-bf16 MFMA GEMM core.
// C[m,n] = (sum_k A[m,k] * B[.,.] + bias[n]) * scale
//   A: fp32 [m][k] natural, reg-staged -> hi/lo bf16 LDS planes (swizzled).
//   B: BT=false: fp32 [n][k];  BT=true: fp32 [k][n] (transpose-staged). BT requires BN==64.
// Tile BM x BN, BK=64, 256 threads = 4 waves (2x2), per-wave (BM/2)x(BN/2).
// LDS rows pitch 128B, 16B-unit XOR swizzle: unit ^= (row&7).
template<int BM, int BN, bool ASPLIT, bool BSPLIT, bool BT>
__device__ __forceinline__ void mgemm(
    const float* __restrict__ A, long lda, int aRvalid,
    const float* __restrict__ B, long ldb, int bRvalid,  // BT: valid k-rows; else valid n-rows
    const float* __restrict__ bias,
    float* __restrict__ C, long ldc,
    int M, int N, int K, float scale,
    int m0, int n0, unsigned char* lds)
{
    constexpr int AH = 0;
    constexpr int AL = AH + BM * 128;
    constexpr int BHo = AL + (ASPLIT ? BM * 128 : 0);
    constexpr int BLo = BHo + BN * 128;
    constexpr int FM = BM / 32, FN = BN / 32;

    const int t = threadIdx.x;
    const int lane = t & 63;
    const int wave = t >> 6;
    const int wm = wave >> 1, wn = wave & 1;

    f32x4 acc[FM][FN];
    #pragma unroll
    for (int i = 0; i < FM; ++i)
        #pragma unroll
        for (int j = 0; j < FN; ++j)
            #pragma unroll
            for (int e = 0; e < 4; ++e) acc[i][j][e] = 0.f;

    for (int k0 = 0; k0 < K; k0 += 64) {
        // ---- stage A: fp32 -> hi/lo planes
        #pragma unroll
        for (int c = 0; c < BM / 16; ++c) {
            const int fi = c * 256 + t;
            const int row = fi >> 4, u4 = fi & 15;
            const int gr = m0 + row;
            float4 f = make_float4(0.f, 0.f, 0.f, 0.f);
            if (gr < aRvalid) f = *(const float4*)(A + (long)gr * lda + k0 + u4 * 4);
            const unsigned short h0 = f2bf(f.x), h1 = f2bf(f.y), h2 = f2bf(f.z), h3 = f2bf(f.w);
            const int byte = row * 128 + ((((u4 >> 1) ^ (row & 7)) << 4) | ((u4 & 1) << 3));
            short4v hv; hv[0] = (short)h0; hv[1] = (short)h1; hv[2] = (short)h2; hv[3] = (short)h3;
            *(short4v*)(lds + AH + byte) = hv;
            if (ASPLIT) {
                short4v lv;
                lv[0] = (short)f2bf(f.x - bfbits2f(h0));
                lv[1] = (short)f2bf(f.y - bfbits2f(h1));
                lv[2] = (short)f2bf(f.z - bfbits2f(h2));
                lv[3] = (short)f2bf(f.w - bfbits2f(h3));
                *(short4v*)(lds + AL + byte) = lv;
            }
        }
        // ---- stage B
        if (!BT) {
            #pragma unroll
            for (int c = 0; c < BN / 16; ++c) {
                const int fi = c * 256 + t;
                const int row = fi >> 4, u4 = fi & 15;
                const int gr = n0 + row;
                float4 f = make_float4(0.f, 0.f, 0.f, 0.f);
                if (gr < bRvalid) f = *(const float4*)(B + (long)gr * ldb + k0 + u4 * 4);
                const unsigned short h0 = f2bf(f.x), h1 = f2bf(f.y), h2 = f2bf(f.z), h3 = f2bf(f.w);
                const int byte = row * 128 + ((((u4 >> 1) ^ (row & 7)) << 4) | ((u4 & 1) << 3));
                short4v hv; hv[0] = (short)h0; hv[1] = (short)h1; hv[2] = (short)h2; hv[3] = (short)h3;
                *(short4v*)(lds + BHo + byte) = hv;
                if (BSPLIT) {
                    short4v lv;
                    lv[0] = (short)f2bf(f.x - bfbits2f(h0));
                    lv[1] = (short)f2bf(f.y - bfbits2f(h1));
                    lv[2] = (short)f2bf(f.z - bfbits2f(h2));
                    lv[3] = (short)f2bf(f.w - bfbits2f(h3));
                    *(short4v*)(lds + BLo + byte) = lv;
                }
            }
        } else {
            // B stored [k][n]: read coalesced over n, transpose into LDS [n][k]
            #pragma unroll
            for (int c = 0; c < 4; ++c) {      // BN==64: 64 k-rows x 16 float4
                const int fi = c * 256 + t;
                const int kl = fi >> 4, n4 = fi & 15;
                float4 f = make_float4(0.f, 0.f, 0.f, 0.f);
                if (k0 + kl < bRvalid) f = *(const float4*)(B + (long)(k0 + kl) * ldb + n0 + n4 * 4);
                float fa[4] = {f.x, f.y, f.z, f.w};
                #pragma unroll
                for (int j = 0; j < 4; ++j) {
                    const int n = n4 * 4 + j;
                    const int byte = n * 128 + ((((kl >> 3) ^ (n & 7)) << 4) | ((kl & 7) << 1));
                    const unsigned short h = f2bf(fa[j]);
                    *(short*)(lds + BHo + byte) = (short)h;
                    if (BSPLIT) *(short*)(lds + BLo + byte) = (short)f2bf(fa[j] - bfbits2f(h));
                }
            }
        }
        __syncthreads();

        // ---- compute: 2 k-slices of 32
        #pragma unroll
        for (int ks = 0; ks < 2; ++ks) {
            short8 ah[FM], al[FM], bh[FN], bl[FN];
            #pragma unroll
            for (int fm = 0; fm < FM; ++fm) {
                const int row = wm * (BM / 2) + fm * 16 + (lane & 15);
                const int byte = row * 128 + (((ks * 4 + (lane >> 4)) ^ (row & 7)) << 4);
                ah[fm] = *(const short8*)(lds + AH + byte);
                if (ASPLIT) al[fm] = *(const short8*)(lds + AL + byte);
            }
            #pragma unroll
            for (int fn = 0; fn < FN; ++fn) {
                const int row = wn * (BN / 2) + fn * 16 + (lane & 15);
                const int byte = row * 128 + (((ks * 4 + (lane >> 4)) ^ (row & 7)) << 4);
                bh[fn] = *(const short8*)(lds + BHo + byte);
                if (BSPLIT) bl[fn] = *(const short8*)(lds + BLo + byte);
            }
            #pragma unroll
            for (int fm = 0; fm < FM; ++fm)
                #pragma unroll
                for (int fn = 0; fn < FN; ++fn) {
                    acc[fm][fn] = __builtin_amdgcn_mfma_f32_16x16x32_bf16(ah[fm], bh[fn], acc[fm][fn], 0, 0, 0);
                    if (ASPLIT)
                        acc[fm][fn] = __builtin_amdgcn_mfma_f32_16x16x32_bf16(al[fm], bh[fn], acc[fm][fn], 0, 0, 0);
                    if (BSPLIT)
                        acc[fm][fn] = __builtin_amdgcn_mfma_f32_16x16x32_bf16(ah[fm], bl[fn], acc[fm][fn], 0, 0, 0);
                }
        }
        __syncthreads();
    }

    // ---- epilogue: row=(lane>>4)*4+i, col=lane&15
    #pragma unroll
    for (int fm = 0; fm < FM; ++fm)
        #pragma unroll
        for (int i = 0; i < 4; ++i) {
            const int m = m0 + wm * (BM / 2) + fm * 16 + ((lane >> 4) << 2) + i;
            if (m >= M) continue;
            #pragma unroll
            for (int fn = 0; fn < FN; ++fn) {
                const int n = n0 + wn * (BN / 2) + fn * 16 + (lane & 15);
                if (n >= N) continue;
                float v = acc[fm][fn][i];
                if (bias) v += bias[n];
                C[(long)m * ldc + n] = v * scale;
            }
        }
}

// ---- fused q/k/v projections: y<8 -> q, y<24 -> k, else v
__global__ __launch_bounds__(256) void qkv_kernel(
    const float* __restrict__ q, const float* __restrict__ k, const float* __restrict__ v,
    const float* __restrict__ ipw, const float* __restrict__ ipb,
    float* __restrict__ qp, float* __restrict__ kp, float* __restrict__ vp, float qscale)
{
    __shared__ __align__(16) unsigned char lds[lds_bytes(64, 64, true, true)];
    const int y = blockIdx.y;
    const float* A; const float* B; const float* bias; float* C;
    int M; float scale; int m0;
    if (y < 8)       { A = q; B = ipw;                  bias = ipb;        C = qp; M = 512;  scale = qscale; m0 = y * 64; }
    else if (y < 24) { A = k; B = ipw + 1024L * 1024;   bias = ipb + 1024; C = kp; M = 1020; scale = 1.f;    m0 = (y - 8) * 64; }
    else             { A = v; B = ipw + 2048L * 1024;   bias = ipb + 2048; C = vp; M = 1020; scale = 1.f;    m0 = (y - 24) * 64; }
    mgemm<64, 64, true, true, false>(A, 1024, M, B, 1024, 1024, bias, C, 1024,
                                     M, 1024, 1024, scale, m0, blockIdx.x * 64, lds);
}

// ---- mask build: mask[b][n'][m] = (r[n'] <= r[m] && c[m] <= c[n']) ? 1 : 0  (fp32, 256x256 zero-padded)
__global__ __launch_bounds__(256) void maskbuild_kernel(
    const int* __restrict__ indices, float* __restrict__ mask)
{
    const int b = blockIdx.x;
    __shared__ int rs[256], cs[256];
    const int tid = threadIdx.x;
    if (tid < TK) {
        rs[tid] = indices[(b * TK + tid) * 2 + 0];
        cs[tid] = indices[(b * TK + tid) * 2 + 1];
    } else {
        rs[tid] = (int)0x80000000;  // sentinel: excluded as m (rn<=rs false) and as n' (cs[m]<=cn false)
        cs[tid] = (int)0x80000000;
    }
    __syncthreads();
    const int ng = tid >> 6, ml = tid & 63;
    const int rm0 = rs[ml * 4 + 0], cm0 = cs[ml * 4 + 0];
    const int rm1 = rs[ml * 4 + 1], cm1 = cs[ml * 4 + 1];
    const int rm2 = rs[ml * 4 + 2], cm2 = cs[ml * 4 + 2];
    const int rm3 = rs[ml * 4 + 3], cm3 = cs[ml * 4 + 3];
    for (int g = 0; g < 64; ++g) {
        const int np = g * 4 + ng;
        const int rn = rs[np], cn = cs[np];
        float4 f;
        f.x = (rn <= rm0 && cm0 <= cn) ? 1.f : 0.f;
        f.y = (rn <= rm1 && cm1 <= cn) ? 1.f : 0.f;
        f.z = (rn <= rm2 && cm2 <= cn) ? 1.f : 0.f;
        f.w = (rn <= rm3 && cm3 <= cn) ? 1.f : 0.f;
        *(float4*)(mask + ((long)b * 256 + np) * 256 + ml * 4) = f;
    }
}

// ---- km[b][n'][e] = sum_m mask[b][n'][m] * kp[(m*4+b)*1024 + e]
__global__ __launch_bounds__(256) void km_kernel(
    const float* __restrict__ mask, const float* __restrict__ kp, float* __restrict__ km)
{
    __shared__ __align__(16) unsigned char lds[lds_bytes(64, 64, false, true)];
    const int b = blockIdx.z;
    mgemm<64, 64, false, true, true>(mask + (long)b * 256 * 256, 256, 256,
                                     kp + (long)b * 1024, 4096, TK,
                                     nullptr, km + (long)b * 256 * 1024, 1024,
                                     256, 1024, 256, 1.f,
                                     blockIdx.y * 64, blockIdx.x * 64, lds);
}

// ---- scores: raw[bh][t][n'] = sum_d qp[t][h*128+d] * km[b][n'][h*128+d]
__global__ __launch_bounds__(256) void scores_kernel(
    const float* __restrict__ qp, const float* __restrict__ km, float* __restrict__ raw)
{
    __shared__ __align__(16) unsigned char lds[lds_bytes(64, 64, true, true)];
    const int bh = blockIdx.z, b = bh >> 3, h = bh & 7;
    mgemm<64, 64, true, true, false>(qp + (long)b * 1024 + h * 128, 4096, 128,
                                     km + (long)b * 256 * 1024 + h * 128, 1024, 256,
                                     nullptr, raw + (long)bh * 128 * 256, 256,
                                     128, 256, 128, 1.f,
                                     blockIdx.y * 64, blockIdx.x * 64, lds);
}

// ---- row softmax over 255 nodes (col 255 -> 0)
__global__ __launch_bounds__(256) void softmax_kernel(
    const float* __restrict__ raw, float* __restrict__ wsoft)
{
    const int row = blockIdx.x * 4 + (threadIdx.x >> 6);
    const int lane = threadIdx.x & 63;
    float4 f = *(const float4*)(raw + (long)row * 256 + lane * 4);
    if (lane == 63) f.w = -INFINITY;
    float mx = fmaxf(fmaxf(f.x, f.y), fmaxf(f.z, f.w));
    #pragma unroll
    for (int off = 32; off; off >>= 1) mx = fmaxf(mx, __shfl_xor(mx, off));
    const float e0 = expf(f.x - mx), e1 = expf(f.y - mx), e2 = expf(f.z - mx), e3 = expf(f.w - mx);
    float s = e0 + e1 + e2 + e3;
    #pragma unroll
    for (int off = 32; off; off >>= 1) s += __shfl_xor(s, off);
    const float inv = 1.f / s;
    float4 o = make_float4(e0 * inv, e1 * inv, e2 * inv, e3 * inv);
    *(float4*)(wsoft + (long)row * 256 + lane * 4) = o;
}

// ---- pv: attn[(t*4+b)*1024 + h*128 + d] = sum_n w[bh][t][n] * vp[(n*4+b)*1024 + h*128 + d]
__global__ __launch_bounds__(256) void pv_kernel(
    const float* __restrict__ wsoft, const float* __restrict__ vp, float* __restrict__ attn)
{
    __shared__ __align__(16) unsigned char lds[lds_bytes(64, 64, true, true)];
    const int bh = blockIdx.z, b = bh >> 3, h = bh & 7;
    mgemm<64, 64, true, true, true>(wsoft + (long)bh * 128 * 256, 256, 128,
                                    vp + (long)b * 1024 + h * 128, 4096, TK,
                                    nullptr, attn + (long)b * 1024 + h * 128, 4096,
                                    128, 128, 256, 1.f,
                                    blockIdx.y * 64, blockIdx.x * 64, lds);
}

// ---- out projection (BM=32 for 256 blocks)
__global__ __launch_bounds__(256) void outproj_kernel(
    const float* __restrict__ attn, const float* __restrict__ opw,
    const float* __restrict__ opb, float* __restrict__ out)
{
    __shared__ __align__(16) unsigned char lds[lds_bytes(32, 64, true, true)];
    mgemm<32, 64, true, true, false>(attn, 1024, 512, opw, 1024, 1024, opb, out, 1024,
                                     512, 1024, 1024, 1.f,
                                     blockIdx.y * 32, blockIdx.x * 64, lds);
}

extern "C" void kernel_launch(void* const* d_in, const int* in_sizes, int n_in,
                              void* d_out, int out_size, void* d_ws, size_t ws_size,
                              hipStream_t stream) {
    const float* query   = (const float*)d_in[0];
    const float* key_t   = (const float*)d_in[1];
    const float* value   = (const float*)d_in[2];
    const int*   indices = (const int*)d_in[3];
    const float* ipw     = (const float*)d_in[4];
    const float* ipb     = (const float*)d_in[5];
    const float* opw     = (const float*)d_in[6];
    const float* opb     = (const float*)d_in[7];
    float* out = (float*)d_out;

    float* ws    = (float*)d_ws;
    float* kp    = ws;                  // [1024][1024] (1020 rows used)
    float* vp    = kp + 1048576;        // [1024][1024]
    float* qp    = vp + 1048576;        // [512][1024]
    float* mask  = qp + 524288;         // [4][256][256]
    float* km    = mask + 262144;       // [4][256][1024]
    float* raw   = km + 1048576;        // [32][128][256]
    float* wsoft = raw + 1048576;       // [32][128][256]
    float* attn  = raw;                 // overlay: raw dead after softmax

    const float qscale = 0.08838834764831843f;  // 128^-0.5

    maskbuild_kernel<<<dim3(BATCH), 256, 0, stream>>>(indices, mask);

    qkv_kernel<<<dim3(16, 40), 256, 0, stream>>>(
        query, key_t, value, ipw, ipb, qp, kp, vp, qscale);

    km_kernel<<<dim3(16, 4, BATCH), 256, 0, stream>>>(mask, kp, km);

    scores_kernel<<<dim3(4, 2, BH), 256, 0, stream>>>(qp, km, raw);

    softmax_kernel<<<dim3(BH * LQ / 4), 256, 0, stream>>>(raw, wsoft);

    pv_kernel<<<dim3(2, 2, BH), 256, 0, stream>>>(wsoft, vp, attn);

    outproj_kernel<<<dim3(16, 16), 256, 0, stream>>>(attn, opw, opb, out);
}

// Round 4
// 104.861 us; speedup vs baseline: 5.9583x; 1.6125x over previous
//
#include <hip/hip_runtime.h>
#include <math.h>

#define EMBED 1024
#define NHEAD 8
#define HDIM 128
#define TK 255
#define BATCH 4
#define LQ 128
#define BH 32

typedef __attribute__((ext_vector_type(4))) float f32x4;
typedef __attribute__((ext_vector_type(8))) short short8;
typedef __attribute__((ext_vector_type(4))) short short4v;

static __device__ __forceinline__ unsigned short f2bf(float f) {
    unsigned u = __float_as_uint(f);
    u += 0x7FFFu + ((u >> 16) & 1u);
    return (unsigned short)(u >> 16);
}
static __device__ __forceinline__ float bfbits2f(unsigned short s) {
    return __uint_as_float(((unsigned)s) << 16);
}

// ============ pack: fp32 [rows][1024] -> bf16 [rows][2048] = [hi | lo] ============
__global__ __launch_bounds__(256) void pack_all(
    const float* __restrict__ query, const float* __restrict__ key_t,
    const float* __restrict__ value, const float* __restrict__ ipw,
    const float* __restrict__ opw,
    unsigned short* __restrict__ apk, unsigned short* __restrict__ wpk)
{
    const int APKC = 2560 * 256;
    const int TOT = APKC + 4096 * 256;
    for (int idx = blockIdx.x * 256 + threadIdx.x; idx < TOT; idx += gridDim.x * 256) {
        const bool isA = idx < APKC;
        const int rel = isA ? idx : idx - APKC;
        const int row = rel >> 8, c4 = rel & 255;
        const float* src = nullptr; long srow = 0;
        unsigned short* dst;
        if (isA) {
            dst = apk + (long)row * 2048;
            if (row < 512) { src = query; srow = row; }
            else if (row < 1536) { if (row - 512 < 1020) { src = key_t; srow = row - 512; } }
            else { if (row - 1536 < 1020) { src = value; srow = row - 1536; } }
        } else {
            dst = wpk + (long)row * 2048;
            if (row < 3072) { src = ipw; srow = row; }
            else { src = opw; srow = row - 3072; }
        }
        float4 f = make_float4(0.f, 0.f, 0.f, 0.f);
        if (src) f = *(const float4*)(src + srow * 1024 + c4 * 4);
        const unsigned short h0 = f2bf(f.x), h1 = f2bf(f.y), h2 = f2bf(f.z), h3 = f2bf(f.w);
        short4v hv, lv;
        hv[0] = (short)h0; hv[1] = (short)h1; hv[2] = (short)h2; hv[3] = (short)h3;
        lv[0] = (short)f2bf(f.x - bfbits2f(h0));
        lv[1] = (short)f2bf(f.y - bfbits2f(h1));
        lv[2] = (short)f2bf(f.z - bfbits2f(h2));
        lv[3] = (short)f2bf(f.w - bfbits2f(h3));
        *(short4v*)(dst + c4 * 4) = hv;
        *(short4v*)(dst + 1024 + c4 * 4) = lv;
    }
}

__global__ __launch_bounds__(256) void pack_attn_kernel(
    const float* __restrict__ attn, unsigned short* __restrict__ apk2)
{
    const int idx = blockIdx.x * 256 + threadIdx.x;   // 512*256
    const int row = idx >> 8, c4 = idx & 255;
    float4 f = *(const float4*)(attn + (long)row * 1024 + c4 * 4);
    const unsigned short h0 = f2bf(f.x), h1 = f2bf(f.y), h2 = f2bf(f.z), h3 = f2bf(f.w);
    short4v hv, lv;
    hv[0] = (short)h0; hv[1] = (short)h1; hv[2] = (short)h2; hv[3] = (short)h3;
    lv[0] = (short)f2bf(f.x - bfbits2f(h0));
    lv[1] = (short)f2bf(f.y - bfbits2f(h1));
    lv[2] = (short)f2bf(f.z - bfbits2f(h2));
    lv[3] = (short)f2bf(f.w - bfbits2f(h3));
    unsigned short* dst = apk2 + (long)row * 2048;
    *(short4v*)(dst + c4 * 4) = hv;
    *(short4v*)(dst + 1024 + c4 * 4) = lv;
}

// ============ pure-bf16 packed GEMM: 24 K-blocks of 128 walking (hi.hi, lo.hi, hi.lo) ====
// A,B: bf16 [rows][2048] = [hi|lo]; C fp32. BK=128, 256 thr = 4 waves (2x2).
// LDS row pitch 256B, 16B-unit XOR swizzle u ^= row&15.
template<int BM, int BN>
__device__ __forceinline__ void bgemm(
    const unsigned short* __restrict__ A,
    const unsigned short* __restrict__ B,
    const float* __restrict__ bias,
    float* __restrict__ C, long ldc, float scale,
    int m0, int n0, unsigned char* lds)
{
    constexpr int AOF = 0, BOF = BM * 256;
    constexpr int FM = BM / 32, FN = BN / 32;
    constexpr int CA = BM / 16, CB = BN / 16;
    const int t = threadIdx.x, lane = t & 63, wave = t >> 6;
    const int wm = wave >> 1, wn = wave & 1;

    f32x4 acc[FM][FN];
    #pragma unroll
    for (int i = 0; i < FM; ++i)
        #pragma unroll
        for (int j = 0; j < FN; ++j)
            #pragma unroll
            for (int e = 0; e < 4; ++e) acc[i][j][e] = 0.f;

    short8 ra[CA], rb[CB];
    #pragma unroll
    for (int c = 0; c < CA; ++c) {
        const int fi = c * 256 + t, row = fi >> 4, u = fi & 15;
        ra[c] = *(const short8*)(A + (long)(m0 + row) * 2048 + u * 8);
    }
    #pragma unroll
    for (int c = 0; c < CB; ++c) {
        const int fi = c * 256 + t, row = fi >> 4, u = fi & 15;
        rb[c] = *(const short8*)(B + (long)(n0 + row) * 2048 + u * 8);
    }

    for (int kt = 0; kt < 24; ++kt) {
        #pragma unroll
        for (int c = 0; c < CA; ++c) {
            const int fi = c * 256 + t, row = fi >> 4, u = fi & 15;
            *(short8*)(lds + AOF + row * 256 + ((u ^ (row & 15)) << 4)) = ra[c];
        }
        #pragma unroll
        for (int c = 0; c < CB; ++c) {
            const int fi = c * 256 + t, row = fi >> 4, u = fi & 15;
            *(short8*)(lds + BOF + row * 256 + ((u ^ (row & 15)) << 4)) = rb[c];
        }
        __syncthreads();
        if (kt + 1 < 24) {
            const int kn = kt + 1;
            const int anext = (kn & 15) << 7;                       // [hi|lo] then hi again
            const int bnext = ((kn & 7) << 7) + (kn >= 16 ? 1024 : 0); // hi, hi, then lo
            #pragma unroll
            for (int c = 0; c < CA; ++c) {
                const int fi = c * 256 + t, row = fi >> 4, u = fi & 15;
                ra[c] = *(const short8*)(A + (long)(m0 + row) * 2048 + anext + u * 8);
            }
            #pragma unroll
            for (int c = 0; c < CB; ++c) {
                const int fi = c * 256 + t, row = fi >> 4, u = fi & 15;
                rb[c] = *(const short8*)(B + (long)(n0 + row) * 2048 + bnext + u * 8);
            }
        }
        #pragma unroll
        for (int ks = 0; ks < 4; ++ks) {
            short8 af[FM], bg[FN];
            #pragma unroll
            for (int fm = 0; fm < FM; ++fm) {
                const int row = wm * (BM / 2) + fm * 16 + (lane & 15);
                const int u = (ks * 4 + (lane >> 4)) ^ (row & 15);
                af[fm] = *(const short8*)(lds + AOF + row * 256 + (u << 4));
            }
            #pragma unroll
            for (int fn = 0; fn < FN; ++fn) {
                const int row = wn * (BN / 2) + fn * 16 + (lane & 15);
                const int u = (ks * 4 + (lane >> 4)) ^ (row & 15);
                bg[fn] = *(const short8*)(lds + BOF + row * 256 + (u << 4));
            }
            #pragma unroll
            for (int fm = 0; fm < FM; ++fm)
                #pragma unroll
                for (int fn = 0; fn < FN; ++fn)
                    acc[fm][fn] = __builtin_amdgcn_mfma_f32_16x16x32_bf16(af[fm], bg[fn], acc[fm][fn], 0, 0, 0);
        }
        __syncthreads();
    }

    #pragma unroll
    for (int fm = 0; fm < FM; ++fm)
        #pragma unroll
        for (int i = 0; i < 4; ++i) {
            const int m = m0 + wm * (BM / 2) + fm * 16 + ((lane >> 4) << 2) + i;
            #pragma unroll
            for (int fn = 0; fn < FN; ++fn) {
                const int n = n0 + wn * (BN / 2) + fn * 16 + (lane & 15);
                float v = acc[fm][fn][i];
                if (bias) v += bias[n];
                C[(long)m * ldc + n] = v * scale;
            }
        }
}

__global__ __launch_bounds__(256) void qkvb_kernel(
    const unsigned short* __restrict__ apk, const unsigned short* __restrict__ wpk,
    const float* __restrict__ ipb,
    float* __restrict__ qp, float* __restrict__ kp, float* __restrict__ vp, float qscale)
{
    __shared__ __align__(16) unsigned char lds[(64 + 64) * 256];
    const int y = blockIdx.y;
    const unsigned short* A; const unsigned short* B; const float* bias; float* C;
    float scale; int m0;
    if (y < 8)       { A = apk;                m0 = y * 64;        B = wpk;                bias = ipb;        C = qp; scale = qscale; }
    else if (y < 24) { A = apk + 512L * 2048;  m0 = (y - 8) * 64;  B = wpk + 1024L * 2048; bias = ipb + 1024; C = kp; scale = 1.f; }
    else             { A = apk + 1536L * 2048; m0 = (y - 24) * 64; B = wpk + 2048L * 2048; bias = ipb + 2048; C = vp; scale = 1.f; }
    bgemm<64, 64>(A, B, bias, C, 1024, scale, m0, blockIdx.x * 64, lds);
}

__global__ __launch_bounds__(256) void outprojb_kernel(
    const unsigned short* __restrict__ apk2, const unsigned short* __restrict__ wpk,
    const float* __restrict__ opb, float* __restrict__ out)
{
    __shared__ __align__(16) unsigned char lds[(32 + 64) * 256];
    bgemm<32, 64>(apk2, wpk + 3072L * 2048, opb, out, 1024, 1.f,
                  blockIdx.y * 32, blockIdx.x * 64, lds);
}

// ============ split-bf16 on-the-fly mgemm (for small qk / pv GEMMs) ============
template<int BM, int BN, bool ASPLIT, bool BSPLIT, bool BT>
__device__ __forceinline__ void mgemm(
    const float* __restrict__ A, long lda, int aRvalid,
    const float* __restrict__ B, long ldb, int bRvalid,
    const float* __restrict__ bias,
    float* __restrict__ C, long ldc,
    int M, int N, int K, float scale,
    int m0, int n0, unsigned char* lds)
{
    constexpr int AH = 0;
    constexpr int AL = AH + BM * 128;
    constexpr int BHo = AL + (ASPLIT ? BM * 128 : 0);
    constexpr int BLo = BHo + BN * 128;
    constexpr int FM = BM / 32, FN = BN / 32;

    const int t = threadIdx.x;
    const int lane = t & 63;
    const int wave = t >> 6;
    const int wm = wave >> 1, wn = wave & 1;

    f32x4 acc[FM][FN];
    #pragma unroll
    for (int i = 0; i < FM; ++i)
        #pragma unroll
        for (int j = 0; j < FN; ++j)
            #pragma unroll
            for (int e = 0; e < 4; ++e) acc[i][j][e] = 0.f;

    for (int k0 = 0; k0 < K; k0 += 64) {
        #pragma unroll
        for (int c = 0; c < BM / 16; ++c) {
            const int fi = c * 256 + t;
            const int row = fi >> 4, u4 = fi & 15;
            const int gr = m0 + row;
            float4 f = make_float4(0.f, 0.f, 0.f, 0.f);
            if (gr < aRvalid) f = *(const float4*)(A + (long)gr * lda + k0 + u4 * 4);
            const unsigned short h0 = f2bf(f.x), h1 = f2bf(f.y), h2 = f2bf(f.z), h3 = f2bf(f.w);
            const int byte = row * 128 + ((((u4 >> 1) ^ (row & 7)) << 4) | ((u4 & 1) << 3));
            short4v hv; hv[0] = (short)h0; hv[1] = (short)h1; hv[2] = (short)h2; hv[3] = (short)h3;
            *(short4v*)(lds + AH + byte) = hv;
            if (ASPLIT) {
                short4v lv;
                lv[0] = (short)f2bf(f.x - bfbits2f(h0));
                lv[1] = (short)f2bf(f.y - bfbits2f(h1));
                lv[2] = (short)f2bf(f.z - bfbits2f(h2));
                lv[3] = (short)f2bf(f.w - bfbits2f(h3));
                *(short4v*)(lds + AL + byte) = lv;
            }
        }
        if (!BT) {
            #pragma unroll
            for (int c = 0; c < BN / 16; ++c) {
                const int fi = c * 256 + t;
                const int row = fi >> 4, u4 = fi & 15;
                const int gr = n0 + row;
                float4 f = make_float4(0.f, 0.f, 0.f, 0.f);
                if (gr < bRvalid) f = *(const float4*)(B + (long)gr * ldb + k0 + u4 * 4);
                const unsigned short h0 = f2bf(f.x), h1 = f2bf(f.y), h2 = f2bf(f.z), h3 = f2bf(f.w);
                const int byte = row * 128 + ((((u4 >> 1) ^ (row & 7)) << 4) | ((u4 & 1) << 3));
                short4v hv; hv[0] = (short)h0; hv[1] = (short)h1; hv[2] = (short)h2; hv[3] = (short)h3;
                *(short4v*)(lds + BHo + byte) = hv;
                if (BSPLIT) {
                    short4v lv;
                    lv[0] = (short)f2bf(f.x - bfbits2f(h0));
                    lv[1] = (short)f2bf(f.y - bfbits2f(h1));
                    lv[2] = (short)f2bf(f.z - bfbits2f(h2));
                    lv[3] = (short)f2bf(f.w - bfbits2f(h3));
                    *(short4v*)(lds + BLo + byte) = lv;
                }
            }
        } else {
            #pragma unroll
            for (int c = 0; c < 4; ++c) {
                const int fi = c * 256 + t;
                const int kl = fi >> 4, n4 = fi & 15;
                float4 f = make_float4(0.f, 0.f, 0.f, 0.f);
                if (k0 + kl < bRvalid) f = *(const float4*)(B + (long)(k0 + kl) * ldb + n0 + n4 * 4);
                float fa[4] = {f.x, f.y, f.z, f.w};
                #pragma unroll
                for (int j = 0; j < 4; ++j) {
                    const int n = n4 * 4 + j;
                    const int byte = n * 128 + ((((kl >> 3) ^ (n & 7)) << 4) | ((kl & 7) << 1));
                    const unsigned short h = f2bf(fa[j]);
                    *(short*)(lds + BHo + byte) = (short)h;
                    if (BSPLIT) *(short*)(lds + BLo + byte) = (short)f2bf(fa[j] - bfbits2f(h));
                }
            }
        }
        __syncthreads();

        #pragma unroll
        for (int ks = 0; ks < 2; ++ks) {
            short8 ah[FM], al[FM], bh[FN], bl[FN];
            #pragma unroll
            for (int fm = 0; fm < FM; ++fm) {
                const int row = wm * (BM / 2) + fm * 16 + (lane & 15);
                const int byte = row * 128 + (((ks * 4 + (lane >> 4)) ^ (row & 7)) << 4);
                ah[fm] = *(const short8*)(lds + AH + byte);
                if (ASPLIT) al[fm] = *(const short8*)(lds + AL + byte);
            }
            #pragma unroll
            for (int fn = 0; fn < FN; ++fn) {
                const int row = wn * (BN / 2) + fn * 16 + (lane & 15);
                const int byte = row * 128 + (((ks * 4 + (lane >> 4)) ^ (row & 7)) << 4);
                bh[fn] = *(const short8*)(lds + BHo + byte);
                if (BSPLIT) bl[fn] = *(const short8*)(lds + BLo + byte);
            }
            #pragma unroll
            for (int fm = 0; fm < FM; ++fm)
                #pragma unroll
                for (int fn = 0; fn < FN; ++fn) {
                    acc[fm][fn] = __builtin_amdgcn_mfma_f32_16x16x32_bf16(ah[fm], bh[fn], acc[fm][fn], 0, 0, 0);
                    if (ASPLIT)
                        acc[fm][fn] = __builtin_amdgcn_mfma_f32_16x16x32_bf16(al[fm], bh[fn], acc[fm][fn], 0, 0, 0);
                    if (BSPLIT)
                        acc[fm][fn] = __builtin_amdgcn_mfma_f32_16x16x32_bf16(ah[fm], bl[fn], acc[fm][fn], 0, 0, 0);
                }
        }
        __syncthreads();
    }

    #pragma unroll
    for (int fm = 0; fm < FM; ++fm)
        #pragma unroll
        for (int i = 0; i < 4; ++i) {
            const int m = m0 + wm * (BM / 2) + fm * 16 + ((lane >> 4) << 2) + i;
            if (m >= M) continue;
            #pragma unroll
            for (int fn = 0; fn < FN; ++fn) {
                const int n = n0 + wn * (BN / 2) + fn * 16 + (lane & 15);
                if (n >= N) continue;
                float v = acc[fm][fn][i];
                if (bias) v += bias[n];
                C[(long)m * ldc + n] = v * scale;
            }
        }
}

// ---- per-head QK^T: raw[bh][t][n] = q_t . k_n
__global__ __launch_bounds__(256) void qk_kernel(
    const float* __restrict__ qp, const float* __restrict__ kp, float* __restrict__ raw)
{
    __shared__ __align__(16) unsigned char lds[64 * 128 * 4];
    const int bh = blockIdx.z, b = bh >> 3, h = bh & 7;
    mgemm<64, 64, true, true, false>(qp + (long)b * 1024 + h * 128, 4096, 128,
                                     kp + (long)b * 1024 + h * 128, 4096, TK,
                                     nullptr, raw + (long)bh * 128 * 256, 256,
                                     128, 256, 128, 1.f,
                                     blockIdx.y * 64, blockIdx.x * 64, lds);
}

// ---- pv: attn[(t*4+b)*1024 + h*128 + d] = sum_n w[t,n] * vp[(n*4+b)*1024 + h*128 + d]
__global__ __launch_bounds__(256) void pv_kernel(
    const float* __restrict__ wsoft, const float* __restrict__ vp, float* __restrict__ attn)
{
    __shared__ __align__(16) unsigned char lds[64 * 128 * 4];
    const int bh = blockIdx.z, b = bh >> 3, h = bh & 7;
    mgemm<64, 64, true, true, true>(wsoft + (long)bh * 128 * 256, 256, 128,
                                    vp + (long)b * 1024 + h * 128, 4096, TK,
                                    nullptr, attn + (long)b * 1024 + h * 128, 4096,
                                    128, 128, 256, 1.f,
                                    blockIdx.y * 64, blockIdx.x * 64, lds);
}

// ============ fused subtree-sum (7 Jacobi sweeps) + row softmax, in place ============
// raw: [BH*LQ][256]; preorder tree: left = n+1, right = n + 2*(mid-r) + 2
__global__ __launch_bounds__(256) void treesm_kernel(
    float* __restrict__ raw, const int* __restrict__ indices)
{
    __shared__ float buf[4][2][256];
    const int wave = threadIdx.x >> 6, lane = threadIdx.x & 63;
    const int row = blockIdx.x * 4 + wave;
    const int b = row >> 10;
    float* R = raw + (long)row * 256;

    float rv[4]; int lch[4], rch[4]; bool lf[4];
    #pragma unroll
    for (int j = 0; j < 4; ++j) {
        const int n = lane + 64 * j;
        float v = 0.f; int l = n, rr = n; bool leaf = true;
        if (n < TK) {
            v = R[n];
            const int r0 = indices[(b * TK + n) * 2 + 0];
            const int c0 = indices[(b * TK + n) * 2 + 1];
            leaf = (r0 == c0);
            const int mid = (r0 + c0) >> 1;
            l = n + 1;
            rr = n + 2 * (mid - r0) + 2;
        }
        rv[j] = v; lf[j] = leaf; lch[j] = l; rch[j] = rr;
        buf[wave][0][n] = v;
    }
    __syncthreads();
    int cur = 0;
    for (int it = 0; it < 7; ++it) {
        float nv[4];
        #pragma unroll
        for (int j = 0; j < 4; ++j)
            nv[j] = lf[j] ? rv[j] : rv[j] + buf[wave][cur][lch[j]] + buf[wave][cur][rch[j]];
        #pragma unroll
        for (int j = 0; j < 4; ++j) buf[wave][cur ^ 1][lane + 64 * j] = nv[j];
        cur ^= 1;
        __syncthreads();
    }
    float v[4]; float mx = -INFINITY;
    #pragma unroll
    for (int j = 0; j < 4; ++j) {
        const int n = lane + 64 * j;
        v[j] = (n < TK) ? buf[wave][cur][n] : -INFINITY;
        mx = fmaxf(mx, v[j]);
    }
    #pragma unroll
    for (int off = 32; off; off >>= 1) mx = fmaxf(mx, __shfl_xor(mx, off));
    float e[4], s = 0.f;
    #pragma unroll
    for (int j = 0; j < 4; ++j) { e[j] = (v[j] <= -INFINITY) ? 0.f : expf(v[j] - mx); s += e[j]; }
    #pragma unroll
    for (int off = 32; off; off >>= 1) s += __shfl_xor(s, off);
    const float inv = 1.f / s;
    #pragma unroll
    for (int j = 0; j < 4; ++j) R[lane + 64 * j] = e[j] * inv;
}

extern "C" void kernel_launch(void* const* d_in, const int* in_sizes, int n_in,
                              void* d_out, int out_size, void* d_ws, size_t ws_size,
                              hipStream_t stream) {
    const float* query   = (const float*)d_in[0];
    const float* key_t   = (const float*)d_in[1];
    const float* value   = (const float*)d_in[2];
    const int*   indices = (const int*)d_in[3];
    const float* ipw     = (const float*)d_in[4];
    const float* ipb     = (const float*)d_in[5];
    const float* opw     = (const float*)d_in[6];
    const float* opb     = (const float*)d_in[7];
    float* out = (float*)d_out;

    float* ws = (float*)d_ws;
    float* kp  = ws;                         // [1024][1024] (rows 1020..1023 pad)
    float* vp  = kp + 1048576;               // [1024][1024]
    float* raw = vp + 1048576;               // [32][128][256], becomes wsoft in place
    float* qp  = raw + 1048576;              // [512][1024], later reused as attn
    unsigned short* apk  = (unsigned short*)(qp + 524288);  // [2560][2048] bf16
    unsigned short* wpk  = apk + 2560L * 2048;              // [4096][2048] bf16
    unsigned short* apk2 = apk;                             // overlay (apk dead after qkvb)
    float* attn = qp;                                       // overlay (qp dead after qk)

    const float qscale = 0.08838834764831843f;  // 128^-0.5

    pack_all<<<dim3(2048), 256, 0, stream>>>(query, key_t, value, ipw, opw, apk, wpk);

    qkvb_kernel<<<dim3(16, 40), 256, 0, stream>>>(apk, wpk, ipb, qp, kp, vp, qscale);

    qk_kernel<<<dim3(4, 2, BH), 256, 0, stream>>>(qp, kp, raw);

    treesm_kernel<<<dim3(BH * LQ / 4), 256, 0, stream>>>(raw, indices);

    pv_kernel<<<dim3(2, 2, BH), 256, 0, stream>>>(raw, vp, attn);

    pack_attn_kernel<<<dim3(512), 256, 0, stream>>>(attn, apk2);

    outprojb_kernel<<<dim3(16, 16), 256, 0, stream>>>(apk2, wpk, opb, out);
}